// Round 15
// baseline (66.585 us; speedup 1.0000x reference)
//
#include <hip/hip_runtime.h>
#include <stdint.h>

// Bahdanau attention: B=64, T=2048, D=256, U=256, all fp32 in/out.
// out = [context (B*D) | attn (B*T)] flat fp32.
#define Bq 64
#define Tq 2048
#define Dq 256
#define Uq 256
#define NTILE 32   // T/64 tiles per batch

typedef __bf16 bf16x8 __attribute__((ext_vector_type(8)));
typedef float f32x4 __attribute__((ext_vector_type(4)));

// A LDS (bf16 RNE, double-buffered): [oct 0..3][row 0..63][16B], no pad
#define ASTR 1024
#define ABUF (4 * ASTR)        // 4096 per buffer
// B LDS (bf16 RNE, double-buffered): [oct 0..3][u 0..255][16B], no pad
#define BSTR 4096
#define BBUF (4 * BSTR)        // 16384 per buffer
// total LDS = 2*16384 + 2*4096 = 40960 -> exactly 4 blocks/CU.
// scp (256 f) + ebuf (64 f) overlay sA (dead after last chunk's ds_reads).

// fp32 -> bf16 round-to-nearest-even (rel err <= 2^-9)
__device__ inline unsigned short rne_bf16(float a) {
  unsigned b = __float_as_uint(a);
  return (unsigned short)((b + 0x7FFFu + ((b >> 16) & 1u)) >> 16);
}

// tanh(x) = 1 - 2/(exp(2x)+1). ~6 VALU ops, saturates correctly.
__device__ inline float fast_tanh(float x) {
  float e = __expf(2.0f * x);
  return 1.0f - 2.0f * __builtin_amdgcn_rcpf(e + 1.0f);
}

// K01 fused:
//  blocks [0,64):   w1 [U][D] fp32 -> bf16 RNE octet-major w1bf
//  blocks [64,4160): comb[b][u] = dot(hidden[b], w2_w[u]) + w2_b[u] + w1_b[u]
__global__ void k01_prep(const float* __restrict__ w1,
                         unsigned short* __restrict__ w1bf,
                         const float* __restrict__ hidden,
                         const float* __restrict__ w2_w,
                         const float* __restrict__ w2_b,
                         const float* __restrict__ w1_b,
                         float* __restrict__ comb) {
  if (blockIdx.x < 64) {
    int idx = blockIdx.x * 256 + threadIdx.x;
    int i = idx * 4;
    int u = i >> 8;
    int k = i & 255;
    float4 v = *reinterpret_cast<const float4*>(&w1[i]);
    ushort4 h;
    h.x = rne_bf16(v.x);
    h.y = rne_bf16(v.y);
    h.z = rne_bf16(v.z);
    h.w = rne_bf16(v.w);
    int dst = (k >> 3) * (Uq * 8) + u * 8 + (k & 7);
    *reinterpret_cast<ushort4*>(&w1bf[dst]) = h;
  } else {
    int bid = blockIdx.x - 64;
    int b = bid >> 6;
    int wave = threadIdx.x >> 6;
    int lane = threadIdx.x & 63;
    int u = (bid & 63) * 4 + wave;
    const float* h = hidden + b * Dq;
    const float* w = w2_w + u * Dq;
    float sum = 0.f;
#pragma unroll
    for (int i = 0; i < Dq; i += 64) sum += h[lane + i] * w[lane + i];
#pragma unroll
    for (int m = 32; m >= 1; m >>= 1) sum += __shfl_xor(sum, m, 64);
    if (lane == 0) comb[b * Uq + u] = sum + w2_b[u] + w1_b[u];
  }
}

// K2: raw score + flash-style partial context for a 64-t tile.
__global__ __launch_bounds__(256, 4) void k2_score(
    const float* __restrict__ feat, const unsigned short* __restrict__ w1bf,
    const float* __restrict__ comb, const float* __restrict__ v_w,
    const float* __restrict__ v_b, float* __restrict__ score,
    float* __restrict__ pm, float* __restrict__ partc) {
  __shared__ char sB[2 * BBUF];
  __shared__ char sA[2 * ABUF];
  float* const scp = reinterpret_cast<float*>(sA);          // 256 floats
  float* const ebuf = reinterpret_cast<float*>(sA) + 256;   // 64 floats
  const int b = blockIdx.y;
  const int tile = blockIdx.x;
  const int t0 = tile * 64;
  const int tid = threadIdx.x;
  const int w = tid >> 6;
  const int l = tid & 63;
  const int fr = l & 15;
  const int g = l >> 4;

  // A staging role: row = tid>>2 (0..63), oct = tid&3; 8 floats per chunk.
  const int arow = tid >> 2;
  const int aoct = tid & 3;
  const float* aload = feat + ((size_t)(b * Tq + t0 + arow)) * Dq + aoct * 8;
  char* const awr = sA + aoct * ASTR + arow * 16;

  f32x4 acc[4][4] = {};
  float4 pa[2][2];

  auto issueBdma = [&](int c) {
    char* bbase = sB + (c & 1) * BBUF;
#pragma unroll
    for (int q = 0; q < 4; ++q) {
      int d = w * 4 + q;         // 0..15
      int j = d >> 2;            // k-octet in chunk
      int h2 = d & 3;            // u-quarter
      const unsigned short* src =
          w1bf + (size_t)(c * 4 + j) * (Uq * 8) + (h2 * 64 + l) * 8;
      __builtin_amdgcn_global_load_lds(
          (const __attribute__((address_space(1))) unsigned int*)src,
          (__attribute__((address_space(3))) unsigned int*)(bbase + j * BSTR +
                                                            h2 * 1024),
          16, 0, 0);
    }
  };
  auto loadA = [&](int c) {
    pa[c & 1][0] = *reinterpret_cast<const float4*>(aload + c * 32);
    pa[c & 1][1] = *reinterpret_cast<const float4*>(aload + c * 32 + 4);
  };
  auto writeA = [&](int c) {
    const float4& v0 = pa[c & 1][0];
    const float4& v1 = pa[c & 1][1];
    uint4 H;
    H.x = rne_bf16(v0.x) | ((unsigned)rne_bf16(v0.y) << 16);
    H.y = rne_bf16(v0.z) | ((unsigned)rne_bf16(v0.w) << 16);
    H.z = rne_bf16(v1.x) | ((unsigned)rne_bf16(v1.y) << 16);
    H.w = rne_bf16(v1.z) | ((unsigned)rne_bf16(v1.w) << 16);
    *reinterpret_cast<uint4*>(awr + (c & 1) * ABUF) = H;
  };
  auto pipeBarrier = [&]() {
    __builtin_amdgcn_sched_barrier(0);
    asm volatile("s_waitcnt vmcnt(2) lgkmcnt(0)" ::: "memory");
    __builtin_amdgcn_s_barrier();
    __builtin_amdgcn_sched_barrier(0);
  };

  // ---- prologue ----
  issueBdma(0);
  __builtin_amdgcn_sched_barrier(0);
  loadA(0);
  loadA(1);
  __builtin_amdgcn_sched_barrier(0);
  writeA(0);
  pipeBarrier();

  // ---- main loop ----
#pragma unroll
  for (int c = 0; c < 8; ++c) {
    if (c < 7) {
      issueBdma(c + 1);
      __builtin_amdgcn_sched_barrier(0);
      loadA((c + 2) & 7);
      __builtin_amdgcn_sched_barrier(0);
    }
    const char* bA = sA + (c & 1) * ABUF;
    const char* bB = sB + (c & 1) * BBUF;
    bf16x8 ah[4], bh[4];
#pragma unroll
    for (int mf = 0; mf < 4; ++mf)
      ah[mf] = *reinterpret_cast<const bf16x8*>(bA + g * ASTR +
                                                (mf * 16 + fr) * 16);
#pragma unroll
    for (int nf = 0; nf < 4; ++nf)
      bh[nf] = *reinterpret_cast<const bf16x8*>(
          bB + g * BSTR + (w * 64 + nf * 16 + fr) * 16);
    __builtin_amdgcn_s_setprio(1);
#pragma unroll
    for (int mf = 0; mf < 4; ++mf)
#pragma unroll
      for (int nf = 0; nf < 4; ++nf)
        acc[mf][nf] = __builtin_amdgcn_mfma_f32_16x16x32_bf16(
            ah[mf], bh[nf], acc[mf][nf], 0, 0, 0);
    __builtin_amdgcn_s_setprio(0);
    if (c < 7) {
      writeA(c + 1);
      pipeBarrier();
    }
  }

  // ---- issue first half of context feature loads EARLY (T14) ----
  const float* frow = feat + (size_t)(b * Tq + t0) * Dq + tid;
  float fv0[16], fv1[16];
#pragma unroll
  for (int t = 0; t < 16; ++t) fv0[t] = frow[(size_t)t * Dq];
#pragma unroll
  for (int t = 0; t < 16; ++t) fv1[t] = frow[(size_t)(t + 16) * Dq];

  // ---- epilogue 1: tanh + v-dot -> raw scores ----
  float cb[4], vw4[4];
#pragma unroll
  for (int nf = 0; nf < 4; ++nf) {
    int u = w * 64 + nf * 16 + fr;
    cb[nf] = comb[b * Uq + u];
    vw4[nf] = v_w[u];
  }
  float sc[4][4];
#pragma unroll
  for (int mf = 0; mf < 4; ++mf)
#pragma unroll
    for (int r = 0; r < 4; ++r) sc[mf][r] = 0.f;
#pragma unroll
  for (int mf = 0; mf < 4; ++mf)
#pragma unroll
    for (int nf = 0; nf < 4; ++nf)
#pragma unroll
      for (int r = 0; r < 4; ++r)
        sc[mf][r] += vw4[nf] * fast_tanh(acc[mf][nf][r] + cb[nf]);
#pragma unroll
  for (int m = 1; m < 16; m <<= 1)
#pragma unroll
    for (int mf = 0; mf < 4; ++mf)
#pragma unroll
      for (int r = 0; r < 4; ++r) sc[mf][r] += __shfl_xor(sc[mf][r], m, 16);
  __syncthreads();   // sA reads done everywhere -> scp/ebuf overlay safe
  if (fr == 0) {
#pragma unroll
    for (int mf = 0; mf < 4; ++mf)
#pragma unroll
      for (int r = 0; r < 4; ++r)
        scp[w * 64 + mf * 16 + g * 4 + r] = sc[mf][r];
  }
  __syncthreads();
  // ---- epilogue 2: finalize scores, block max, exp weights ----
  if (tid < 64) {
    float v =
        scp[tid] + scp[64 + tid] + scp[128 + tid] + scp[192 + tid] + v_b[0];
    score[b * Tq + t0 + tid] = v;
    float m = v;
#pragma unroll
    for (int mk = 32; mk >= 1; mk >>= 1) m = fmaxf(m, __shfl_xor(m, mk, 64));
    ebuf[tid] = __expf(v - m);
    if (tid == 0) pm[b * NTILE + tile] = m;
  }
  __syncthreads();
  // ---- epilogue 3: partial context; second half interleaved ----
  {
    float fv2[16], fv3[16];
#pragma unroll
    for (int t = 0; t < 16; ++t) fv2[t] = frow[(size_t)(t + 32) * Dq];
    float cd = 0.f;
#pragma unroll
    for (int t = 0; t < 16; ++t) cd += ebuf[t] * fv0[t];
#pragma unroll
    for (int t = 0; t < 16; ++t) fv3[t] = frow[(size_t)(t + 48) * Dq];
#pragma unroll
    for (int t = 0; t < 16; ++t) cd += ebuf[t + 16] * fv1[t];
#pragma unroll
    for (int t = 0; t < 16; ++t) cd += ebuf[t + 32] * fv2[t];
#pragma unroll
    for (int t = 0; t < 16; ++t) cd += ebuf[t + 48] * fv3[t];
    partc[((size_t)b * NTILE + tile) * Dq + tid] = cd;
  }
}

// K35 fused: softmax over T per batch (in place) + context combine.
__global__ void k35_softmax_combine(float* __restrict__ s,
                                    const float* __restrict__ pm,
                                    const float* __restrict__ partc,
                                    float* __restrict__ ctx) {
  int b = blockIdx.x;
  int tid = threadIdx.x;
  const int base = b * Tq;
  float v[8];
  float m = -1e30f;
#pragma unroll
  for (int i = 0; i < 8; ++i) {
    v[i] = s[base + tid + 256 * i];
    m = fmaxf(m, v[i]);
  }
#pragma unroll
  for (int mk = 32; mk >= 1; mk >>= 1) m = fmaxf(m, __shfl_xor(m, mk, 64));
  __shared__ float red[4];
  int wv = tid >> 6, ln = tid & 63;
  if (ln == 0) red[wv] = m;
  __syncthreads();
  m = fmaxf(fmaxf(red[0], red[1]), fmaxf(red[2], red[3]));
  __syncthreads();
  float sum = 0.f;
#pragma unroll
  for (int i = 0; i < 8; ++i) {
    v[i] = __expf(v[i] - m);
    sum += v[i];
  }
#pragma unroll
  for (int mk = 32; mk >= 1; mk >>= 1) sum += __shfl_xor(sum, mk, 64);
  if (ln == 0) red[wv] = sum;
  __syncthreads();
  sum = red[0] + red[1] + red[2] + red[3];
  float inv = 1.f / sum;
#pragma unroll
  for (int i = 0; i < 8; ++i) s[base + tid + 256 * i] = v[i] * inv;

  __shared__ float wgt[NTILE];
  if (tid < NTILE) wgt[tid] = __expf(pm[b * NTILE + tid] - m);
  __syncthreads();
  float cs = 0.f;
#pragma unroll
  for (int j = 0; j < NTILE; ++j)
    cs += wgt[j] * partc[((size_t)b * NTILE + j) * Dq + tid];
  ctx[b * Dq + tid] = cs * inv;
}

extern "C" void kernel_launch(void* const* d_in, const int* in_sizes, int n_in,
                              void* d_out, int out_size, void* d_ws,
                              size_t ws_size, hipStream_t stream) {
  const float* feat   = (const float*)d_in[0];
  const float* hidden = (const float*)d_in[1];
  const float* w1_w   = (const float*)d_in[2];
  const float* w1_b   = (const float*)d_in[3];
  const float* w2_w   = (const float*)d_in[4];
  const float* w2_b   = (const float*)d_in[5];
  const float* v_w    = (const float*)d_in[6];
  const float* v_b    = (const float*)d_in[7];

  float* ctx  = (float*)d_out;             // [B][D]
  float* attn = ctx + Bq * Dq;             // [B][T] (raw score -> softmax)
  float* comb = (float*)d_ws;              // [B][U]            64 KB
  unsigned short* w1bf = (unsigned short*)(comb + Bq * Uq);   // 128 KB
  float* partc = (float*)(w1bf + Uq * Dq); // [B][32][D]        2 MB
  float* pm    = partc + (size_t)Bq * NTILE * Dq;  // [B][32]   8 KB

  k01_prep<<<64 + Bq * 64, 256, 0, stream>>>(w1_w, w1bf, hidden, w2_w, w2_b,
                                             w1_b, comb);
  k2_score<<<dim3(NTILE, Bq), 256, 0, stream>>>(feat, w1bf, comb, v_w, v_b,
                                                attn, pm, partc);
  k35_softmax_combine<<<Bq, 256, 0, stream>>>(attn, pm, partc, ctx);
}

// Round 16
// 61.625 us; speedup vs baseline: 1.0805x; 1.0805x over previous
//
#include <hip/hip_runtime.h>
#include <stdint.h>

// Bahdanau attention: B=64, T=2048, D=256, U=256, all fp32 in/out.
// out = [context (B*D) | attn (B*T)] flat fp32.
#define Bq 64
#define Tq 2048
#define Dq 256
#define Uq 256
#define NTILE 32   // T/64 tiles per batch

typedef __bf16 bf16x8 __attribute__((ext_vector_type(8)));
typedef float f32x4 __attribute__((ext_vector_type(4)));

// A LDS (bf16 RNE, double-buffered): [oct 0..3][row 0..63][16B], no pad
#define ASTR 1024
#define ABUF (4 * ASTR)        // 4096 per buffer
// B LDS (bf16 RNE, double-buffered): [oct 0..3][u 0..255][16B], no pad
#define BSTR 4096
#define BBUF (4 * BSTR)        // 16384 per buffer
// total LDS = 2*16384 + 2*4096 = 40960 -> exactly 4 blocks/CU.
// scp (256 f) + ebuf (64 f) overlay sA (dead after last chunk's ds_reads).
// NOTE: no min-waves in __launch_bounds__ — r15's (256,4) clamped VGPR to 64
// and spilled the context arrays to scratch (+64MB FETCH, +56MB WRITE).
// Natural allocation (~108 VGPR) already fits 4 waves/SIMD.

// fp32 -> bf16 round-to-nearest-even (rel err <= 2^-9)
__device__ inline unsigned short rne_bf16(float a) {
  unsigned b = __float_as_uint(a);
  return (unsigned short)((b + 0x7FFFu + ((b >> 16) & 1u)) >> 16);
}

// tanh(x) = 1 - 2/(exp(2x)+1). ~6 VALU ops, saturates correctly.
__device__ inline float fast_tanh(float x) {
  float e = __expf(2.0f * x);
  return 1.0f - 2.0f * __builtin_amdgcn_rcpf(e + 1.0f);
}

// K01 fused:
//  blocks [0,64):   w1 [U][D] fp32 -> bf16 RNE octet-major w1bf
//  blocks [64,4160): comb[b][u] = dot(hidden[b], w2_w[u]) + w2_b[u] + w1_b[u]
__global__ void k01_prep(const float* __restrict__ w1,
                         unsigned short* __restrict__ w1bf,
                         const float* __restrict__ hidden,
                         const float* __restrict__ w2_w,
                         const float* __restrict__ w2_b,
                         const float* __restrict__ w1_b,
                         float* __restrict__ comb) {
  if (blockIdx.x < 64) {
    int idx = blockIdx.x * 256 + threadIdx.x;
    int i = idx * 4;
    int u = i >> 8;
    int k = i & 255;
    float4 v = *reinterpret_cast<const float4*>(&w1[i]);
    ushort4 h;
    h.x = rne_bf16(v.x);
    h.y = rne_bf16(v.y);
    h.z = rne_bf16(v.z);
    h.w = rne_bf16(v.w);
    int dst = (k >> 3) * (Uq * 8) + u * 8 + (k & 7);
    *reinterpret_cast<ushort4*>(&w1bf[dst]) = h;
  } else {
    int bid = blockIdx.x - 64;
    int b = bid >> 6;
    int wave = threadIdx.x >> 6;
    int lane = threadIdx.x & 63;
    int u = (bid & 63) * 4 + wave;
    const float* h = hidden + b * Dq;
    const float* w = w2_w + u * Dq;
    float sum = 0.f;
#pragma unroll
    for (int i = 0; i < Dq; i += 64) sum += h[lane + i] * w[lane + i];
#pragma unroll
    for (int m = 32; m >= 1; m >>= 1) sum += __shfl_xor(sum, m, 64);
    if (lane == 0) comb[b * Uq + u] = sum + w2_b[u] + w1_b[u];
  }
}

// K2: raw score + flash-style partial context for a 64-t tile.
__global__ __launch_bounds__(256) void k2_score(
    const float* __restrict__ feat, const unsigned short* __restrict__ w1bf,
    const float* __restrict__ comb, const float* __restrict__ v_w,
    const float* __restrict__ v_b, float* __restrict__ score,
    float* __restrict__ pm, float* __restrict__ partc) {
  __shared__ char sB[2 * BBUF];
  __shared__ char sA[2 * ABUF];
  float* const scp = reinterpret_cast<float*>(sA);          // 256 floats
  float* const ebuf = reinterpret_cast<float*>(sA) + 256;   // 64 floats
  const int b = blockIdx.y;
  const int tile = blockIdx.x;
  const int t0 = tile * 64;
  const int tid = threadIdx.x;
  const int w = tid >> 6;
  const int l = tid & 63;
  const int fr = l & 15;
  const int g = l >> 4;

  // A staging role: row = tid>>2 (0..63), oct = tid&3; 8 floats per chunk.
  const int arow = tid >> 2;
  const int aoct = tid & 3;
  const float* aload = feat + ((size_t)(b * Tq + t0 + arow)) * Dq + aoct * 8;
  char* const awr = sA + aoct * ASTR + arow * 16;

  f32x4 acc[4][4] = {};
  float4 pa[2][2];

  auto issueBdma = [&](int c) {
    char* bbase = sB + (c & 1) * BBUF;
#pragma unroll
    for (int q = 0; q < 4; ++q) {
      int d = w * 4 + q;         // 0..15
      int j = d >> 2;            // k-octet in chunk
      int h2 = d & 3;            // u-quarter
      const unsigned short* src =
          w1bf + (size_t)(c * 4 + j) * (Uq * 8) + (h2 * 64 + l) * 8;
      __builtin_amdgcn_global_load_lds(
          (const __attribute__((address_space(1))) unsigned int*)src,
          (__attribute__((address_space(3))) unsigned int*)(bbase + j * BSTR +
                                                            h2 * 1024),
          16, 0, 0);
    }
  };
  auto loadA = [&](int c) {
    pa[c & 1][0] = *reinterpret_cast<const float4*>(aload + c * 32);
    pa[c & 1][1] = *reinterpret_cast<const float4*>(aload + c * 32 + 4);
  };
  auto writeA = [&](int c) {
    const float4& v0 = pa[c & 1][0];
    const float4& v1 = pa[c & 1][1];
    uint4 H;
    H.x = rne_bf16(v0.x) | ((unsigned)rne_bf16(v0.y) << 16);
    H.y = rne_bf16(v0.z) | ((unsigned)rne_bf16(v0.w) << 16);
    H.z = rne_bf16(v1.x) | ((unsigned)rne_bf16(v1.y) << 16);
    H.w = rne_bf16(v1.z) | ((unsigned)rne_bf16(v1.w) << 16);
    *reinterpret_cast<uint4*>(awr + (c & 1) * ABUF) = H;
  };
  auto pipeBarrier = [&]() {
    __builtin_amdgcn_sched_barrier(0);
    asm volatile("s_waitcnt vmcnt(2) lgkmcnt(0)" ::: "memory");
    __builtin_amdgcn_s_barrier();
    __builtin_amdgcn_sched_barrier(0);
  };

  // ---- prologue ----
  issueBdma(0);
  __builtin_amdgcn_sched_barrier(0);
  loadA(0);
  loadA(1);
  __builtin_amdgcn_sched_barrier(0);
  writeA(0);
  pipeBarrier();

  // ---- main loop ----
#pragma unroll
  for (int c = 0; c < 8; ++c) {
    if (c < 7) {
      issueBdma(c + 1);
      __builtin_amdgcn_sched_barrier(0);
      loadA((c + 2) & 7);
      __builtin_amdgcn_sched_barrier(0);
    }
    const char* bA = sA + (c & 1) * ABUF;
    const char* bB = sB + (c & 1) * BBUF;
    bf16x8 ah[4], bh[4];
#pragma unroll
    for (int mf = 0; mf < 4; ++mf)
      ah[mf] = *reinterpret_cast<const bf16x8*>(bA + g * ASTR +
                                                (mf * 16 + fr) * 16);
#pragma unroll
    for (int nf = 0; nf < 4; ++nf)
      bh[nf] = *reinterpret_cast<const bf16x8*>(
          bB + g * BSTR + (w * 64 + nf * 16 + fr) * 16);
    __builtin_amdgcn_s_setprio(1);
#pragma unroll
    for (int mf = 0; mf < 4; ++mf)
#pragma unroll
      for (int nf = 0; nf < 4; ++nf)
        acc[mf][nf] = __builtin_amdgcn_mfma_f32_16x16x32_bf16(
            ah[mf], bh[nf], acc[mf][nf], 0, 0, 0);
    __builtin_amdgcn_s_setprio(0);
    if (c < 7) {
      writeA(c + 1);
      pipeBarrier();
    }
  }

  // ---- issue first half of context feature loads EARLY (T14) ----
  const float* frow = feat + (size_t)(b * Tq + t0) * Dq + tid;
  float fv0[16], fv1[16];
#pragma unroll
  for (int t = 0; t < 16; ++t) fv0[t] = frow[(size_t)t * Dq];
#pragma unroll
  for (int t = 0; t < 16; ++t) fv1[t] = frow[(size_t)(t + 16) * Dq];

  // ---- epilogue 1: tanh + v-dot -> raw scores ----
  float cb[4], vw4[4];
#pragma unroll
  for (int nf = 0; nf < 4; ++nf) {
    int u = w * 64 + nf * 16 + fr;
    cb[nf] = comb[b * Uq + u];
    vw4[nf] = v_w[u];
  }
  float sc[4][4];
#pragma unroll
  for (int mf = 0; mf < 4; ++mf)
#pragma unroll
    for (int r = 0; r < 4; ++r) sc[mf][r] = 0.f;
#pragma unroll
  for (int mf = 0; mf < 4; ++mf)
#pragma unroll
    for (int nf = 0; nf < 4; ++nf)
#pragma unroll
      for (int r = 0; r < 4; ++r)
        sc[mf][r] += vw4[nf] * fast_tanh(acc[mf][nf][r] + cb[nf]);
#pragma unroll
  for (int m = 1; m < 16; m <<= 1)
#pragma unroll
    for (int mf = 0; mf < 4; ++mf)
#pragma unroll
      for (int r = 0; r < 4; ++r) sc[mf][r] += __shfl_xor(sc[mf][r], m, 16);
  __syncthreads();   // sA reads done everywhere -> scp/ebuf overlay safe
  if (fr == 0) {
#pragma unroll
    for (int mf = 0; mf < 4; ++mf)
#pragma unroll
      for (int r = 0; r < 4; ++r)
        scp[w * 64 + mf * 16 + g * 4 + r] = sc[mf][r];
  }
  __syncthreads();
  // ---- epilogue 2: finalize scores, block max, exp weights ----
  if (tid < 64) {
    float v =
        scp[tid] + scp[64 + tid] + scp[128 + tid] + scp[192 + tid] + v_b[0];
    score[b * Tq + t0 + tid] = v;
    float m = v;
#pragma unroll
    for (int mk = 32; mk >= 1; mk >>= 1) m = fmaxf(m, __shfl_xor(m, mk, 64));
    ebuf[tid] = __expf(v - m);
    if (tid == 0) pm[b * NTILE + tile] = m;
  }
  __syncthreads();
  // ---- epilogue 3: partial context; second half interleaved ----
  {
    float fv2[16], fv3[16];
#pragma unroll
    for (int t = 0; t < 16; ++t) fv2[t] = frow[(size_t)(t + 32) * Dq];
    float cd = 0.f;
#pragma unroll
    for (int t = 0; t < 16; ++t) cd += ebuf[t] * fv0[t];
#pragma unroll
    for (int t = 0; t < 16; ++t) fv3[t] = frow[(size_t)(t + 48) * Dq];
#pragma unroll
    for (int t = 0; t < 16; ++t) cd += ebuf[t + 16] * fv1[t];
#pragma unroll
    for (int t = 0; t < 16; ++t) cd += ebuf[t + 32] * fv2[t];
#pragma unroll
    for (int t = 0; t < 16; ++t) cd += ebuf[t + 48] * fv3[t];
    partc[((size_t)b * NTILE + tile) * Dq + tid] = cd;
  }
}

// K35 fused: softmax over T per batch (in place) + context combine.
__global__ void k35_softmax_combine(float* __restrict__ s,
                                    const float* __restrict__ pm,
                                    const float* __restrict__ partc,
                                    float* __restrict__ ctx) {
  int b = blockIdx.x;
  int tid = threadIdx.x;
  const int base = b * Tq;
  float v[8];
  float m = -1e30f;
#pragma unroll
  for (int i = 0; i < 8; ++i) {
    v[i] = s[base + tid + 256 * i];
    m = fmaxf(m, v[i]);
  }
#pragma unroll
  for (int mk = 32; mk >= 1; mk >>= 1) m = fmaxf(m, __shfl_xor(m, mk, 64));
  __shared__ float red[4];
  int wv = tid >> 6, ln = tid & 63;
  if (ln == 0) red[wv] = m;
  __syncthreads();
  m = fmaxf(fmaxf(red[0], red[1]), fmaxf(red[2], red[3]));
  __syncthreads();
  float sum = 0.f;
#pragma unroll
  for (int i = 0; i < 8; ++i) {
    v[i] = __expf(v[i] - m);
    sum += v[i];
  }
#pragma unroll
  for (int mk = 32; mk >= 1; mk >>= 1) sum += __shfl_xor(sum, mk, 64);
  if (ln == 0) red[wv] = sum;
  __syncthreads();
  sum = red[0] + red[1] + red[2] + red[3];
  float inv = 1.f / sum;
#pragma unroll
  for (int i = 0; i < 8; ++i) s[base + tid + 256 * i] = v[i] * inv;

  __shared__ float wgt[NTILE];
  if (tid < NTILE) wgt[tid] = __expf(pm[b * NTILE + tid] - m);
  __syncthreads();
  float cs = 0.f;
#pragma unroll
  for (int j = 0; j < NTILE; ++j)
    cs += wgt[j] * partc[((size_t)b * NTILE + j) * Dq + tid];
  ctx[b * Dq + tid] = cs * inv;
}

extern "C" void kernel_launch(void* const* d_in, const int* in_sizes, int n_in,
                              void* d_out, int out_size, void* d_ws,
                              size_t ws_size, hipStream_t stream) {
  const float* feat   = (const float*)d_in[0];
  const float* hidden = (const float*)d_in[1];
  const float* w1_w   = (const float*)d_in[2];
  const float* w1_b   = (const float*)d_in[3];
  const float* w2_w   = (const float*)d_in[4];
  const float* w2_b   = (const float*)d_in[5];
  const float* v_w    = (const float*)d_in[6];
  const float* v_b    = (const float*)d_in[7];

  float* ctx  = (float*)d_out;             // [B][D]
  float* attn = ctx + Bq * Dq;             // [B][T] (raw score -> softmax)
  float* comb = (float*)d_ws;              // [B][U]            64 KB
  unsigned short* w1bf = (unsigned short*)(comb + Bq * Uq);   // 128 KB
  float* partc = (float*)(w1bf + Uq * Dq); // [B][32][D]        2 MB
  float* pm    = partc + (size_t)Bq * NTILE * Dq;  // [B][32]   8 KB

  k01_prep<<<64 + Bq * 64, 256, 0, stream>>>(w1_w, w1bf, hidden, w2_w, w2_b,
                                             w1_b, comb);
  k2_score<<<dim3(NTILE, Bq), 256, 0, stream>>>(feat, w1bf, comb, v_w, v_b,
                                                attn, pm, partc);
  k35_softmax_combine<<<Bq, 256, 0, stream>>>(attn, pm, partc, ctx);
}